// Round 3
// baseline (259.783 us; speedup 1.0000x reference)
//
#include <hip/hip_runtime.h>
#include <hip/hip_bf16.h>

#define B_ 4
#define T_ 8192
#define D_ 512
#define H_ 512
#define M_ (B_ * T_)            // 32768 rows of x
#define CHUNK_ 128              // GEMM m-tile = scan chunk
#define SUB_ 32                 // scan sub-chunk (parallelism granule)
#define NSUB_ (T_ / SUB_)       // 256 sub-chunks per sequence
#define SEQS_ (B_ * H_)         // 2048 independent scan sequences

typedef __attribute__((ext_vector_type(8))) short bf16x8;
typedef __attribute__((ext_vector_type(4))) float f32x4;

__device__ __forceinline__ unsigned short f2bf(float x) {
  union { float f; unsigned int u; } c; c.f = x;
  unsigned int u = c.u;
  unsigned int r = (u + 0x7fffu + ((u >> 16) & 1u)) >> 16;  // RTNE
  return (unsigned short)r;
}
__device__ __forceinline__ float bf2f(unsigned short h) {
  union { unsigned int u; float f; } c; c.u = ((unsigned int)h) << 16;
  return c.f;
}

// async 16B/lane global->LDS: lds dest is wave-uniform base, HW adds lane*16
__device__ __forceinline__ void gll16(const void* g, void* l) {
  __builtin_amdgcn_global_load_lds(
      (const __attribute__((address_space(1))) unsigned int*)g,
      (__attribute__((address_space(3))) unsigned int*)l, 16, 0, 0);
}

// ---------------------------------------------------------------------------
// Kernel 1: W_f/W_i/W_h fp32 [D][H] -> Wt bf16 [3][H][D].
// k-inner mapping: ushort4 coalesced writes; strided reads hit L2 (W = 3MB).
// ---------------------------------------------------------------------------
__global__ void wt_convert(const float* __restrict__ Wf, const float* __restrict__ Wi,
                           const float* __restrict__ Wh, unsigned short* __restrict__ Wt) {
  int e = blockIdx.x * 256 + threadIdx.x;   // 196608 total (4 k's each)
  int g = e >> 16;                          // / (512*128)
  int rem = e & 65535;
  int n = rem >> 7;
  int k4 = (rem & 127) * 4;
  const float* W = (g == 0) ? Wf : (g == 1) ? Wi : Wh;
  ushort4 o;
  o.x = f2bf(W[(k4 + 0) * H_ + n]);
  o.y = f2bf(W[(k4 + 1) * H_ + n]);
  o.z = f2bf(W[(k4 + 2) * H_ + n]);
  o.w = f2bf(W[(k4 + 3) * H_ + n]);
  *(ushort4*)(Wt + ((size_t)g * H_ + n) * D_ + k4) = o;
}

// ---------------------------------------------------------------------------
// Kernel 2: x fp32 -> bf16.
// ---------------------------------------------------------------------------
__global__ void x_convert(const float* __restrict__ x, unsigned short* __restrict__ xb) {
  size_t i = ((size_t)blockIdx.x * 256 + threadIdx.x) * 8;
  float4 a = *(const float4*)(x + i);
  float4 b = *(const float4*)(x + i + 4);
  ushort4 ha; ha.x = f2bf(a.x); ha.y = f2bf(a.y); ha.z = f2bf(a.z); ha.w = f2bf(a.w);
  ushort4 hb; hb.x = f2bf(b.x); hb.y = f2bf(b.y); hb.z = f2bf(b.z); hb.w = f2bf(b.w);
  *(ushort4*)(xb + i) = ha;
  *(ushort4*)(xb + i + 4) = hb;
}

// ---------------------------------------------------------------------------
// Kernel 3: fused 3-gate GEMM + gate epilogue + per-sub-chunk (F,S) scan.
// BM=128(=CHUNK), BN=64, BK=64; 256 threads = 4 waves, wave tile 64x32 x3 gates.
// After MFMA: AV tile -> global + LDS; 4 segs x 32 t scan -> Fc/Sc[sub][seq].
// ---------------------------------------------------------------------------
__global__ __launch_bounds__(256, 2)
void gemm_gates(const unsigned short* __restrict__ xb, const unsigned short* __restrict__ Wt,
                const float* __restrict__ bF, const float* __restrict__ bI,
                const float* __restrict__ bH, unsigned int* __restrict__ AV,
                float* __restrict__ Fc, float* __restrict__ Sc) {
  __shared__ unsigned short xs[128 * 64];     // 16 KB
  __shared__ unsigned short wsm[3 * 64 * 64]; // 24 KB
  __shared__ unsigned int avs[128 * 64];      // 32 KB (epilogue scan)

  const int tid = threadIdx.x;
  const int hb = blockIdx.x;          // 0..7  (n-tile)
  const int m0 = blockIdx.y * 128;    // m-tile = one scan chunk
  const int n0 = hb * 64;
  const int wave = tid >> 6;
  const int lane = tid & 63;
  const int wm = (wave & 1) * 64;
  const int wn = (wave >> 1) * 32;
  const int l16 = lane & 15;
  const int quad = lane >> 4;

  // staging lane geometry: 1KB instr = 8 rows x 128B; swizzle chunk ^= row&7
  const int lrow = lane >> 3;
  const int lch = (lane & 7) ^ lrow;

  int xoff[4];
  #pragma unroll
  for (int j = 0; j < 4; ++j) {
    const int gx = wave * 4 + j;
    xoff[j] = (m0 + gx * 8 + lrow) * D_ + lch * 8;
  }
  int woff[6], wdst[6];
  #pragma unroll
  for (int q = 0; q < 6; ++q) {
    const int gw = wave * 6 + q;
    const int g = gw >> 3, rg = gw & 7;
    woff[q] = (g * H_ + n0 + rg * 8 + lrow) * D_ + lch * 8;
    wdst[q] = g * 4096 + rg * 512;
  }

  f32x4 acc[3][4][2];
  #pragma unroll
  for (int g = 0; g < 3; ++g)
    #pragma unroll
    for (int mi = 0; mi < 4; ++mi)
      #pragma unroll
      for (int ni = 0; ni < 2; ++ni)
        acc[g][mi][ni] = (f32x4){0.f, 0.f, 0.f, 0.f};

  #pragma unroll 1
  for (int kb = 0; kb < D_; kb += 64) {
    #pragma unroll
    for (int j = 0; j < 4; ++j)
      gll16(xb + xoff[j] + kb, xs + (wave * 4 + j) * 512);
    #pragma unroll
    for (int q = 0; q < 6; ++q)
      gll16(Wt + woff[q] + kb, wsm + wdst[q]);
    __syncthreads();

    #pragma unroll
    for (int kk = 0; kk < 64; kk += 32) {
      const int kc = kk >> 3;
      bf16x8 af[4];
      #pragma unroll
      for (int mi = 0; mi < 4; ++mi) {
        const int r = wm + mi * 16 + l16;
        af[mi] = *(const bf16x8*)(xs + r * 64 + ((kc + quad) ^ (r & 7)) * 8);
      }
      bf16x8 bfr[3][2];
      #pragma unroll
      for (int g = 0; g < 3; ++g)
        #pragma unroll
        for (int ni = 0; ni < 2; ++ni) {
          const int r = wn + ni * 16 + l16;
          bfr[g][ni] = *(const bf16x8*)(wsm + g * 4096 + r * 64 + ((kc + quad) ^ (r & 7)) * 8);
        }
      #pragma unroll
      for (int g = 0; g < 3; ++g)
        #pragma unroll
        for (int mi = 0; mi < 4; ++mi)
          #pragma unroll
          for (int ni = 0; ni < 2; ++ni)
            acc[g][mi][ni] = __builtin_amdgcn_mfma_f32_16x16x32_bf16(
                af[mi], bfr[g][ni], acc[g][mi][ni], 0, 0, 0);
    }
    __syncthreads();
  }

  // epilogue: C/D layout col=lane&15, row=quad*4+reg
  const size_t avbase = ((size_t)blockIdx.y * 8 + hb) * (CHUNK_ * 64);
  #pragma unroll
  for (int ni = 0; ni < 2; ++ni) {
    const int col = n0 + wn + ni * 16 + l16;
    const int hl = wn + ni * 16 + l16;
    const float bfv = bF[col], biv = bI[col], bhv = bH[col];
    #pragma unroll
    for (int mi = 0; mi < 4; ++mi) {
      const int tb = wm + mi * 16 + quad * 4;
      #pragma unroll
      for (int r = 0; r < 4; ++r) {
        float fp = acc[0][mi][ni][r] + bfv;
        float ip = acc[1][mi][ni][r] + biv;
        float hp = acc[2][mi][ni][r] + bhv;
        fp = fminf(fmaxf(fp, -30.f), 30.f);
        ip = fminf(fmaxf(ip, -30.f), 30.f);
        hp = fminf(fmaxf(hp, -30.f), 30.f);
        const float Ef = __expf(-fp);
        const float Ei = __expf(-ip);
        const float rr2 = 1.f / (2.f + Ef + Ei);
        const float fgate = (1.f + Ei) * rr2;   // forget gate
        const float igate = (1.f + Ef) * rr2;   // input gate = 1-f
        float gval;
        if (hp >= 0.f) gval = hp + 0.5f;
        else gval = 1.f / (1.f + __expf(-hp));
        const float vval = igate * gval;
        const int t = tb + r;
        const unsigned int packed =
            (unsigned int)f2bf(fgate) | ((unsigned int)f2bf(vval) << 16);
        AV[avbase + (size_t)t * 64 + hl] = packed;
        // LDS copy, column-swizzled by (t>>2)&3 so writes are <=2-way banked
        avs[t * 64 + (hl ^ (((t >> 2) & 3) << 4))] = packed;
      }
    }
  }
  __syncthreads();

  // per-sub-chunk scan: thread = (seg, hl); 32 serial steps from LDS
  const int seg = tid >> 6;
  const int shl = tid & 63;
  float F = 1.f, S = 0.f;
  #pragma unroll 8
  for (int t = seg * SUB_; t < seg * SUB_ + SUB_; ++t) {
    const unsigned int w = avs[t * 64 + (shl ^ (((t >> 2) & 3) << 4))];
    const float a = bf2f((unsigned short)(w & 0xffffu));
    const float v = bf2f((unsigned short)(w >> 16));
    F *= a;
    S = fmaf(a, S, v);
  }
  const int bb = m0 >> 13;                 // batch
  const int cc = (m0 & 8191) >> 7;         // chunk within batch
  const int sidx = cc * 4 + seg;           // sub-chunk within batch [0,256)
  const int seq = bb * 512 + n0 + shl;
  Fc[(size_t)sidx * SEQS_ + seq] = F;      // [sub][seq]: coalesced
  Sc[(size_t)sidx * SEQS_ + seq] = S;
}

// ---------------------------------------------------------------------------
// Kernel 4: carry scan over 256 sub-chunks per sequence; writes out[:,0,:].
// ---------------------------------------------------------------------------
__global__ void scan_pass2(const float* __restrict__ h0, const float* __restrict__ Fc,
                           const float* __restrict__ Sc, float* __restrict__ Hin,
                           float* __restrict__ out) {
  const int s = blockIdx.x * 256 + threadIdx.x;     // 0..2047
  const int b = s >> 9;
  const int h = s & 511;
  float x = h0[s];
  float hcur = (x >= 0.f) ? (x + 0.5f) : (1.f / (1.f + __expf(-x)));
  out[(size_t)(b * (T_ + 1)) * H_ + h] = hcur;
  #pragma unroll 8
  for (int c = 0; c < NSUB_; ++c) {
    Hin[(size_t)c * SEQS_ + s] = hcur;
    hcur = fmaf(Fc[(size_t)c * SEQS_ + s], hcur, Sc[(size_t)c * SEQS_ + s]);
  }
}

// ---------------------------------------------------------------------------
// Kernel 5: fix-up — rerun 32-step sub-chunk recurrence with carried h_in.
// 524288 threads (8 blocks/CU) for latency hiding.
// ---------------------------------------------------------------------------
__global__ void scan_pass3(const unsigned int* __restrict__ AV,
                           const float* __restrict__ Hin, float* __restrict__ out) {
  const int gid = blockIdx.x * 256 + threadIdx.x;
  const int hl = gid & 63;
  const int rest = gid >> 6;          // 13 bits: b(2) c(6) sub(2) hb(3)
  const int hbi = rest & 7;
  const int sub = (rest >> 3) & 3;
  const int c = (rest >> 5) & 63;
  const int b = rest >> 11;
  const unsigned int* p = AV + (size_t)((b * 64 + c) * 8 + hbi) * (CHUNK_ * 64)
                             + sub * SUB_ * 64 + hl;
  float* o = out + ((size_t)(b * (T_ + 1) + c * CHUNK_ + sub * SUB_ + 1) * H_)
                 + hbi * 64 + hl;
  const int seq = b * 512 + hbi * 64 + hl;
  float hcur = Hin[(size_t)(c * 4 + sub) * SEQS_ + seq];
  #pragma unroll 8
  for (int t = 0; t < SUB_; ++t) {
    const unsigned int w = p[t * 64];
    const float a = bf2f((unsigned short)(w & 0xffffu));
    const float v = bf2f((unsigned short)(w >> 16));
    hcur = fmaf(a, hcur, v);
    o[(size_t)t * H_] = hcur;
  }
}

extern "C" void kernel_launch(void* const* d_in, const int* in_sizes, int n_in,
                              void* d_out, int out_size, void* d_ws, size_t ws_size,
                              hipStream_t stream) {
  const float* x  = (const float*)d_in[0];
  const float* h0 = (const float*)d_in[1];
  const float* Wf = (const float*)d_in[2];
  const float* bF = (const float*)d_in[3];
  const float* Wi = (const float*)d_in[4];
  const float* bI = (const float*)d_in[5];
  const float* Wh = (const float*)d_in[6];
  const float* bH = (const float*)d_in[7];
  float* out = (float*)d_out;

  char* ws = (char*)d_ws;
  size_t off = 0;
  unsigned int* AV = (unsigned int*)(ws + off);      off += (size_t)M_ * H_ * 4;      // 64 MB
  unsigned short* xbf = (unsigned short*)(ws + off); off += (size_t)M_ * D_ * 2;      // 32 MB
  unsigned short* Wt = (unsigned short*)(ws + off);  off += (size_t)3 * H_ * D_ * 2;  // 1.5 MB
  float* Fc  = (float*)(ws + off); off += (size_t)NSUB_ * SEQS_ * 4;                  // 2 MB
  float* Sc  = (float*)(ws + off); off += (size_t)NSUB_ * SEQS_ * 4;                  // 2 MB
  float* Hin = (float*)(ws + off); off += (size_t)NSUB_ * SEQS_ * 4;                  // 2 MB

  wt_convert<<<(3 * H_ * D_ / 4) / 256, 256, 0, stream>>>(Wf, Wi, Wh, Wt);
  x_convert<<<(M_ * D_) / (256 * 8), 256, 0, stream>>>(x, xbf);
  gemm_gates<<<dim3(H_ / 64, M_ / 128), 256, 0, stream>>>(xbf, Wt, bF, bI, bH, AV, Fc, Sc);
  scan_pass2<<<SEQS_ / 256, 256, 0, stream>>>(h0, Fc, Sc, Hin, out);
  scan_pass3<<<(SEQS_ * (T_ / SUB_)) / 256, 256, 0, stream>>>(AV, Hin, out);
}

// Round 5
// 229.793 us; speedup vs baseline: 1.1305x; 1.1305x over previous
//
#include <hip/hip_runtime.h>
#include <hip/hip_bf16.h>

#define B_ 4
#define T_ 8192
#define D_ 512
#define H_ 512
#define M_ (B_ * T_)            // 32768 rows of x
#define CHUNK_ 128              // GEMM m-tile
#define SUB_ 32                 // scan sub-chunk granule
#define NSUB_ (T_ / SUB_)       // 256 sub-chunks per sequence
#define SEQS_ (B_ * H_)         // 2048 scan sequences

typedef __attribute__((ext_vector_type(8))) short bf16x8;
typedef __attribute__((ext_vector_type(4))) float f32x4;

__device__ __forceinline__ unsigned short f2bf(float x) {
  union { float f; unsigned int u; } c; c.f = x;
  unsigned int u = c.u;
  unsigned int r = (u + 0x7fffu + ((u >> 16) & 1u)) >> 16;  // RTNE
  return (unsigned short)r;
}
__device__ __forceinline__ float bf2f(unsigned short h) {
  union { unsigned int u; float f; } c; c.u = ((unsigned int)h) << 16;
  return c.f;
}

// async 16B/lane global->LDS: lds dest is wave-uniform base, HW adds lane*16
__device__ __forceinline__ void gll16(const void* g, void* l) {
  __builtin_amdgcn_global_load_lds(
      (const __attribute__((address_space(1))) unsigned int*)g,
      (__attribute__((address_space(3))) unsigned int*)l, 16, 0, 0);
}

// ---------------------------------------------------------------------------
// Kernel 1: fused conversions.
//   x fp32 -> xbf bf16 (bulk, all threads)
//   W_f/W_i/W_h fp32[D][H] -> Wt bf16[3][H][D] (first 196608 threads extra)
// ---------------------------------------------------------------------------
__global__ void convert_all(const float* __restrict__ x, const float* __restrict__ Wf,
                            const float* __restrict__ Wi, const float* __restrict__ Wh,
                            unsigned short* __restrict__ xbf, unsigned short* __restrict__ Wt) {
  const int gid = blockIdx.x * 256 + threadIdx.x;   // 4194304 threads
  const size_t i = (size_t)gid * 4;
  const float4 a = *(const float4*)(x + i);
  ushort4 hv;
  hv.x = f2bf(a.x); hv.y = f2bf(a.y); hv.z = f2bf(a.z); hv.w = f2bf(a.w);
  *(ushort4*)(xbf + i) = hv;
  if (gid < 3 * H_ * D_ / 4) {
    const int g = gid >> 16;
    const int rem = gid & 65535;
    const int n = rem >> 7;
    const int k4 = (rem & 127) * 4;
    const float* W = (g == 0) ? Wf : (g == 1) ? Wi : Wh;
    ushort4 o;
    o.x = f2bf(W[(k4 + 0) * H_ + n]);
    o.y = f2bf(W[(k4 + 1) * H_ + n]);
    o.z = f2bf(W[(k4 + 2) * H_ + n]);
    o.w = f2bf(W[(k4 + 3) * H_ + n]);
    *(ushort4*)(Wt + ((size_t)g * H_ + n) * D_ + k4) = o;
  }
}

// ---------------------------------------------------------------------------
// Kernel 2: fused 3-gate GEMM + gate epilogue (R2 structure, unchanged).
// BM=128, BN=64, BK=64; 256 threads = 4 waves, wave tile 64x32 x3 gates.
// LDS XOR-swizzled; global_load_lds width-16 staging; 0 bank conflicts.
// AV chunk-blocked: [(b*64+c)*8+hb][128 t][64 hl] (uint bf16 pairs).
// ---------------------------------------------------------------------------
__global__ __launch_bounds__(256, 2)
void gemm_gates(const unsigned short* __restrict__ xb, const unsigned short* __restrict__ Wt,
                const float* __restrict__ bF, const float* __restrict__ bI,
                const float* __restrict__ bH, unsigned int* __restrict__ AV) {
  __shared__ unsigned short xs[128 * 64];     // 16 KB
  __shared__ unsigned short wsm[3 * 64 * 64]; // 24 KB

  const int tid = threadIdx.x;
  const int hb = blockIdx.x;          // 0..7  (n-tile)
  const int m0 = blockIdx.y * 128;    // m-tile = one scan chunk
  const int n0 = hb * 64;
  const int wave = tid >> 6;
  const int lane = tid & 63;
  const int wm = (wave & 1) * 64;
  const int wn = (wave >> 1) * 32;
  const int l16 = lane & 15;
  const int quad = lane >> 4;
  const int lrow = lane >> 3;
  const int lch = (lane & 7) ^ lrow;

  int xoff[4];
  #pragma unroll
  for (int j = 0; j < 4; ++j)
    xoff[j] = (m0 + (wave * 4 + j) * 8 + lrow) * D_ + lch * 8;
  int woff[6], wdst[6];
  #pragma unroll
  for (int q = 0; q < 6; ++q) {
    const int gw = wave * 6 + q;
    const int g = gw >> 3, rg = gw & 7;
    woff[q] = (g * H_ + n0 + rg * 8 + lrow) * D_ + lch * 8;
    wdst[q] = g * 4096 + rg * 512;
  }

  f32x4 acc[3][4][2];
  #pragma unroll
  for (int g = 0; g < 3; ++g)
    #pragma unroll
    for (int mi = 0; mi < 4; ++mi)
      #pragma unroll
      for (int ni = 0; ni < 2; ++ni)
        acc[g][mi][ni] = (f32x4){0.f, 0.f, 0.f, 0.f};

  #pragma unroll 1
  for (int kb = 0; kb < D_; kb += 64) {
    #pragma unroll
    for (int j = 0; j < 4; ++j)
      gll16(xb + xoff[j] + kb, xs + (wave * 4 + j) * 512);
    #pragma unroll
    for (int q = 0; q < 6; ++q)
      gll16(Wt + woff[q] + kb, wsm + wdst[q]);
    __syncthreads();

    #pragma unroll
    for (int kk = 0; kk < 64; kk += 32) {
      const int kc = kk >> 3;
      bf16x8 af[4];
      #pragma unroll
      for (int mi = 0; mi < 4; ++mi) {
        const int r = wm + mi * 16 + l16;
        af[mi] = *(const bf16x8*)(xs + r * 64 + ((kc + quad) ^ (r & 7)) * 8);
      }
      bf16x8 bfr[3][2];
      #pragma unroll
      for (int g = 0; g < 3; ++g)
        #pragma unroll
        for (int ni = 0; ni < 2; ++ni) {
          const int r = wn + ni * 16 + l16;
          bfr[g][ni] = *(const bf16x8*)(wsm + g * 4096 + r * 64 + ((kc + quad) ^ (r & 7)) * 8);
        }
      #pragma unroll
      for (int g = 0; g < 3; ++g)
        #pragma unroll
        for (int mi = 0; mi < 4; ++mi)
          #pragma unroll
          for (int ni = 0; ni < 2; ++ni)
            acc[g][mi][ni] = __builtin_amdgcn_mfma_f32_16x16x32_bf16(
                af[mi], bfr[g][ni], acc[g][mi][ni], 0, 0, 0);
    }
    __syncthreads();
  }

  // epilogue: C/D layout col=lane&15, row=quad*4+reg
  const size_t avbase = ((size_t)blockIdx.y * 8 + hb) * (CHUNK_ * 64);
  #pragma unroll
  for (int ni = 0; ni < 2; ++ni) {
    const int hl = wn + ni * 16 + l16;
    const int col = n0 + hl;
    const float bfv = bF[col], biv = bI[col], bhv = bH[col];
    #pragma unroll
    for (int mi = 0; mi < 4; ++mi) {
      const int tb = wm + mi * 16 + quad * 4;
      #pragma unroll
      for (int r = 0; r < 4; ++r) {
        float fp = acc[0][mi][ni][r] + bfv;
        float ip = acc[1][mi][ni][r] + biv;
        float hp = acc[2][mi][ni][r] + bhv;
        fp = fminf(fmaxf(fp, -30.f), 30.f);
        ip = fminf(fmaxf(ip, -30.f), 30.f);
        hp = fminf(fmaxf(hp, -30.f), 30.f);
        const float Ef = __expf(-fp);
        const float Ei = __expf(-ip);
        const float rr2 = 1.f / (2.f + Ef + Ei);
        const float fgate = (1.f + Ei) * rr2;   // forget gate
        const float igate = (1.f + Ef) * rr2;   // input gate = 1-f
        float gval;
        if (hp >= 0.f) gval = hp + 0.5f;
        else gval = 1.f / (1.f + __expf(-hp));
        const float vval = igate * gval;
        AV[avbase + (size_t)(tb + r) * 64 + hl] =
            (unsigned int)f2bf(fgate) | ((unsigned int)f2bf(vval) << 16);
      }
    }
  }
}

// ---------------------------------------------------------------------------
// Kernel 3: per-sub-chunk (F,S). Thread = (b,c,sub,hb,hl); 32-iter loops,
// 2048 blocks (8/CU) for latency hiding. Fc/Sc layout [sub_in_batch][seq].
// ---------------------------------------------------------------------------
__global__ void scan_pass1(const unsigned int* __restrict__ AV,
                           float* __restrict__ Fc, float* __restrict__ Sc) {
  const int gid = blockIdx.x * 256 + threadIdx.x;
  const int hl = gid & 63;
  const int rest = gid >> 6;          // hbi(3) sub(2) c(6) b(2)
  const int hbi = rest & 7;
  const int sub = (rest >> 3) & 3;
  const int c = (rest >> 5) & 63;
  const int b = rest >> 11;
  const unsigned int* p = AV + (size_t)((b * 64 + c) * 8 + hbi) * (CHUNK_ * 64)
                             + sub * SUB_ * 64 + hl;
  float F = 1.f, S = 0.f;
  #pragma unroll 8
  for (int t = 0; t < SUB_; ++t) {
    const unsigned int w = p[t * 64];
    const float a = bf2f((unsigned short)(w & 0xffffu));
    const float v = bf2f((unsigned short)(w >> 16));
    F *= a;
    S = fmaf(a, S, v);
  }
  const int sidx = c * 4 + sub;
  const int seq = b * 512 + hbi * 64 + hl;
  Fc[(size_t)sidx * SEQS_ + seq] = F;
  Sc[(size_t)sidx * SEQS_ + seq] = S;
}

// ---------------------------------------------------------------------------
// Kernel 4: carry scan, LDS-local. Block owns 32 seqs: stages all 256
// sub-chunk (F,S) into LDS (64 KB), hierarchical scan (8 grps x 32 subs),
// writes Hin for every sub-chunk and out[:,0,:]. 64 blocks.
// ---------------------------------------------------------------------------
__global__ __launch_bounds__(256, 2)
void scan_pass2(const float* __restrict__ h0, const float* __restrict__ Fc,
                const float* __restrict__ Sc, float* __restrict__ Hin,
                float* __restrict__ out) {
  __shared__ float Fs[NSUB_ * 32];    // 32 KB  [sub][sl]
  __shared__ float Ss[NSUB_ * 32];    // 32 KB
  __shared__ float Fg[8 * 32], Sg[8 * 32], Hg[8 * 32];

  const int tid = threadIdx.x;
  const int seq0 = blockIdx.x * 32;

  #pragma unroll 8
  for (int i = tid; i < NSUB_ * 32; i += 256) {
    const int sub = i >> 5;
    const int sl = i & 31;
    Fs[i] = Fc[(size_t)sub * SEQS_ + seq0 + sl];
    Ss[i] = Sc[(size_t)sub * SEQS_ + seq0 + sl];
  }
  __syncthreads();

  const int g = tid >> 5;             // group 0..7 (32 subs each)
  const int sl = tid & 31;            // seq lane
  {
    float F = 1.f, S = 0.f;
    #pragma unroll 8
    for (int j = 0; j < 32; ++j) {
      const int idx = (g * 32 + j) * 32 + sl;
      S = fmaf(Fs[idx], S, Ss[idx]);
      F *= Fs[idx];
    }
    Fg[g * 32 + sl] = F;
    Sg[g * 32 + sl] = S;
  }
  __syncthreads();

  if (tid < 32) {
    const int seq = seq0 + tid;
    const int b = seq >> 9;
    const int h = seq & 511;
    const float xv = h0[seq];
    float hcur = (xv >= 0.f) ? (xv + 0.5f) : (1.f / (1.f + __expf(-xv)));
    out[(size_t)(b * (T_ + 1)) * H_ + h] = hcur;
    #pragma unroll
    for (int gg = 0; gg < 8; ++gg) {
      Hg[gg * 32 + tid] = hcur;
      hcur = fmaf(Fg[gg * 32 + tid], hcur, Sg[gg * 32 + tid]);
    }
  }
  __syncthreads();

  float h = Hg[g * 32 + sl];
  #pragma unroll 8
  for (int j = 0; j < 32; ++j) {
    const int sub = g * 32 + j;
    const int idx = sub * 32 + sl;
    Hin[(size_t)sub * SEQS_ + seq0 + sl] = h;
    h = fmaf(Fs[idx], h, Ss[idx]);
  }
}

// ---------------------------------------------------------------------------
// Kernel 5: fix-up — replay 32-step sub-chunks with carried h_in (R3-proven).
// 2048 blocks.
// ---------------------------------------------------------------------------
__global__ void scan_pass3(const unsigned int* __restrict__ AV,
                           const float* __restrict__ Hin, float* __restrict__ out) {
  const int gid = blockIdx.x * 256 + threadIdx.x;
  const int hl = gid & 63;
  const int rest = gid >> 6;          // hbi(3) sub(2) c(6) b(2)
  const int hbi = rest & 7;
  const int sub = (rest >> 3) & 3;
  const int c = (rest >> 5) & 63;
  const int b = rest >> 11;
  const unsigned int* p = AV + (size_t)((b * 64 + c) * 8 + hbi) * (CHUNK_ * 64)
                             + sub * SUB_ * 64 + hl;
  float* o = out + ((size_t)(b * (T_ + 1) + c * CHUNK_ + sub * SUB_ + 1) * H_)
                 + hbi * 64 + hl;
  const int seq = b * 512 + hbi * 64 + hl;
  float hcur = Hin[(size_t)(c * 4 + sub) * SEQS_ + seq];
  #pragma unroll 8
  for (int t = 0; t < SUB_; ++t) {
    const unsigned int w = p[t * 64];
    const float a = bf2f((unsigned short)(w & 0xffffu));
    const float v = bf2f((unsigned short)(w >> 16));
    hcur = fmaf(a, hcur, v);
    o[(size_t)t * H_] = hcur;
  }
}

extern "C" void kernel_launch(void* const* d_in, const int* in_sizes, int n_in,
                              void* d_out, int out_size, void* d_ws, size_t ws_size,
                              hipStream_t stream) {
  const float* x  = (const float*)d_in[0];
  const float* h0 = (const float*)d_in[1];
  const float* Wf = (const float*)d_in[2];
  const float* bF = (const float*)d_in[3];
  const float* Wi = (const float*)d_in[4];
  const float* bI = (const float*)d_in[5];
  const float* Wh = (const float*)d_in[6];
  const float* bH = (const float*)d_in[7];
  float* out = (float*)d_out;

  char* ws = (char*)d_ws;
  size_t off = 0;
  unsigned int* AV = (unsigned int*)(ws + off);      off += (size_t)M_ * H_ * 4;      // 64 MB
  unsigned short* xbf = (unsigned short*)(ws + off); off += (size_t)M_ * D_ * 2;      // 32 MB
  unsigned short* Wt = (unsigned short*)(ws + off);  off += (size_t)3 * H_ * D_ * 2;  // 1.5 MB
  float* Fc  = (float*)(ws + off); off += (size_t)NSUB_ * SEQS_ * 4;                  // 2 MB
  float* Sc  = (float*)(ws + off); off += (size_t)NSUB_ * SEQS_ * 4;                  // 2 MB
  float* Hin = (float*)(ws + off); off += (size_t)NSUB_ * SEQS_ * 4;                  // 2 MB

  convert_all<<<(M_ * D_ / 4) / 256, 256, 0, stream>>>(x, Wf, Wi, Wh, xbf, Wt);
  gemm_gates<<<dim3(H_ / 64, M_ / 128), 256, 0, stream>>>(xbf, Wt, bF, bI, bH, AV);
  scan_pass1<<<(SEQS_ * NSUB_) / 256, 256, 0, stream>>>(AV, Fc, Sc);
  scan_pass2<<<SEQS_ / 32, 256, 0, stream>>>(h0, Fc, Sc, Hin, out);
  scan_pass3<<<(SEQS_ * NSUB_) / 256, 256, 0, stream>>>(AV, Hin, out);
}

// Round 6
// 222.135 us; speedup vs baseline: 1.1695x; 1.0345x over previous
//
#include <hip/hip_runtime.h>
#include <hip/hip_bf16.h>

#define B_ 4
#define T_ 8192
#define D_ 512
#define H_ 512
#define M_ (B_ * T_)            // 32768 rows of x
#define CHUNK_ 128              // GEMM m-tile
#define SUB_ 32                 // scan sub-chunk granule
#define NSUB_ (T_ / SUB_)       // 256 sub-chunks per sequence
#define SEQS_ (B_ * H_)         // 2048 scan sequences

typedef __attribute__((ext_vector_type(8))) short bf16x8;
typedef __attribute__((ext_vector_type(4))) float f32x4;

__device__ __forceinline__ unsigned short f2bf(float x) {
  union { float f; unsigned int u; } c; c.f = x;
  unsigned int u = c.u;
  unsigned int r = (u + 0x7fffu + ((u >> 16) & 1u)) >> 16;  // RTNE
  return (unsigned short)r;
}
__device__ __forceinline__ float bf2f(unsigned short h) {
  union { unsigned int u; float f; } c; c.u = ((unsigned int)h) << 16;
  return c.f;
}

// async 16B/lane global->LDS: lds dest is wave-uniform base, HW adds lane*16
__device__ __forceinline__ void gll16(const void* g, void* l) {
  __builtin_amdgcn_global_load_lds(
      (const __attribute__((address_space(1))) unsigned int*)g,
      (__attribute__((address_space(3))) unsigned int*)l, 16, 0, 0);
}

// ---------------------------------------------------------------------------
// Kernel 1: fused conversions (x fp32 -> bf16; W -> Wt bf16 [3][H][D]).
// ---------------------------------------------------------------------------
__global__ void convert_all(const float* __restrict__ x, const float* __restrict__ Wf,
                            const float* __restrict__ Wi, const float* __restrict__ Wh,
                            unsigned short* __restrict__ xbf, unsigned short* __restrict__ Wt) {
  const int gid = blockIdx.x * 256 + threadIdx.x;   // 4194304 threads
  const size_t i = (size_t)gid * 4;
  const float4 a = *(const float4*)(x + i);
  ushort4 hv;
  hv.x = f2bf(a.x); hv.y = f2bf(a.y); hv.z = f2bf(a.z); hv.w = f2bf(a.w);
  *(ushort4*)(xbf + i) = hv;
  if (gid < 3 * H_ * D_ / 4) {
    const int g = gid >> 16;
    const int rem = gid & 65535;
    const int n = rem >> 7;
    const int k4 = (rem & 127) * 4;
    const float* W = (g == 0) ? Wf : (g == 1) ? Wi : Wh;
    ushort4 o;
    o.x = f2bf(W[(k4 + 0) * H_ + n]);
    o.y = f2bf(W[(k4 + 1) * H_ + n]);
    o.z = f2bf(W[(k4 + 2) * H_ + n]);
    o.w = f2bf(W[(k4 + 3) * H_ + n]);
    *(ushort4*)(Wt + ((size_t)g * H_ + n) * D_ + k4) = o;
  }
}

// ---------------------------------------------------------------------------
// Kernel 2: fused 3-gate GEMM + gate epilogue + in-register sub-chunk (F,S).
// XCD-swizzled 1D grid: all 8 hb-blocks of an m-tile land on one XCD,
// temporally adjacent -> x-tile fetched once into that XCD's L2.
// Epilogue composes per-sub-chunk affine (F,S) via ordered shfl_xor butterfly
// (replaces scan_pass1; uses bf16-rounded a,v so carries match pass3 replay).
// ---------------------------------------------------------------------------
__global__ __launch_bounds__(256, 2)
void gemm_gates(const unsigned short* __restrict__ xb, const unsigned short* __restrict__ Wt,
                const float* __restrict__ bF, const float* __restrict__ bI,
                const float* __restrict__ bH, unsigned int* __restrict__ AV,
                float* __restrict__ Fc, float* __restrict__ Sc) {
  __shared__ unsigned short xs[128 * 64];     // 16 KB
  __shared__ unsigned short wsm[3 * 64 * 64]; // 24 KB

  const int tid = threadIdx.x;
  const int bid = blockIdx.x;          // 0..2047
  const int xcd = bid & 7;
  const int kseq = bid >> 3;
  const int mc = (kseq & ~7) | xcd;    // chunk 0..255 (xcd-affine)
  const int hb = kseq & 7;             // n-tile 0..7 (same xcd, adjacent time)
  const int m0 = mc * CHUNK_;
  const int n0 = hb * 64;

  const int wave = tid >> 6;
  const int lane = tid & 63;
  const int wm = (wave & 1) * 64;
  const int wn = (wave >> 1) * 32;
  const int l16 = lane & 15;
  const int quad = lane >> 4;
  const int lrow = lane >> 3;
  const int lch = (lane & 7) ^ lrow;   // XOR swizzle (conflict-free)

  int xoff[4];
  #pragma unroll
  for (int j = 0; j < 4; ++j)
    xoff[j] = (m0 + (wave * 4 + j) * 8 + lrow) * D_ + lch * 8;
  int woff[6], wdst[6];
  #pragma unroll
  for (int q = 0; q < 6; ++q) {
    const int gw = wave * 6 + q;
    const int g = gw >> 3, rg = gw & 7;
    woff[q] = (g * H_ + n0 + rg * 8 + lrow) * D_ + lch * 8;
    wdst[q] = g * 4096 + rg * 512;
  }

  f32x4 acc[3][4][2];
  #pragma unroll
  for (int g = 0; g < 3; ++g)
    #pragma unroll
    for (int mi = 0; mi < 4; ++mi)
      #pragma unroll
      for (int ni = 0; ni < 2; ++ni)
        acc[g][mi][ni] = (f32x4){0.f, 0.f, 0.f, 0.f};

  #pragma unroll 1
  for (int kb = 0; kb < D_; kb += 64) {
    #pragma unroll
    for (int j = 0; j < 4; ++j)
      gll16(xb + xoff[j] + kb, xs + (wave * 4 + j) * 512);
    #pragma unroll
    for (int q = 0; q < 6; ++q)
      gll16(Wt + woff[q] + kb, wsm + wdst[q]);
    __syncthreads();

    #pragma unroll
    for (int kk = 0; kk < 64; kk += 32) {
      const int kc = kk >> 3;
      bf16x8 af[4];
      #pragma unroll
      for (int mi = 0; mi < 4; ++mi) {
        const int r = wm + mi * 16 + l16;
        af[mi] = *(const bf16x8*)(xs + r * 64 + ((kc + quad) ^ (r & 7)) * 8);
      }
      bf16x8 bfr[3][2];
      #pragma unroll
      for (int g = 0; g < 3; ++g)
        #pragma unroll
        for (int ni = 0; ni < 2; ++ni) {
          const int r = wn + ni * 16 + l16;
          bfr[g][ni] = *(const bf16x8*)(wsm + g * 4096 + r * 64 + ((kc + quad) ^ (r & 7)) * 8);
        }
      #pragma unroll
      for (int g = 0; g < 3; ++g)
        #pragma unroll
        for (int mi = 0; mi < 4; ++mi)
          #pragma unroll
          for (int ni = 0; ni < 2; ++ni)
            acc[g][mi][ni] = __builtin_amdgcn_mfma_f32_16x16x32_bf16(
                af[mi], bfr[g][ni], acc[g][mi][ni], 0, 0, 0);
    }
    __syncthreads();
  }

  // epilogue: C/D layout col=lane&15, row=quad*4+reg
  const size_t avbase = ((size_t)mc * 8 + hb) * (CHUNK_ * 64);
  const int bb = mc >> 6, cc = mc & 63;
  #pragma unroll
  for (int ni = 0; ni < 2; ++ni) {
    const int hl = wn + ni * 16 + l16;
    const int col = n0 + hl;
    const float bfv = bF[col], biv = bI[col], bhv = bH[col];
    float Fseg[4], Sseg[4];
    #pragma unroll
    for (int mi = 0; mi < 4; ++mi) {
      const int tb = wm + mi * 16 + quad * 4;
      float Fs_ = 1.f, Ss_ = 0.f;
      #pragma unroll
      for (int r = 0; r < 4; ++r) {
        float fp = acc[0][mi][ni][r] + bfv;
        float ip = acc[1][mi][ni][r] + biv;
        float hp = acc[2][mi][ni][r] + bhv;
        fp = fminf(fmaxf(fp, -30.f), 30.f);
        ip = fminf(fmaxf(ip, -30.f), 30.f);
        hp = fminf(fmaxf(hp, -30.f), 30.f);
        const float Ef = __expf(-fp);
        const float Ei = __expf(-ip);
        const float rr2 = 1.f / (2.f + Ef + Ei);
        const float fgate = (1.f + Ei) * rr2;   // forget gate
        const float igate = (1.f + Ef) * rr2;   // input gate = 1-f
        float gval;
        if (hp >= 0.f) gval = hp + 0.5f;
        else gval = 1.f / (1.f + __expf(-hp));
        const float vval = igate * gval;
        const unsigned short ab = f2bf(fgate);
        const unsigned short vb = f2bf(vval);
        AV[avbase + (size_t)(tb + r) * 64 + hl] =
            (unsigned int)ab | ((unsigned int)vb << 16);
        // compose with the bf16-rounded values (matches pass3's replay)
        const float ar = bf2f(ab), vr = bf2f(vb);
        Ss_ = fmaf(ar, Ss_, vr);
        Fs_ *= ar;
      }
      Fseg[mi] = Fs_; Sseg[mi] = Ss_;
    }
    // ordered quad-reduction (t ascends with quad for fixed mi)
    #pragma unroll
    for (int mi = 0; mi < 4; ++mi) {
      float F = Fseg[mi], S = Sseg[mi];
      float Fo = __shfl_xor(F, 16);
      float So = __shfl_xor(S, 16);
      S = (quad & 1) ? fmaf(F, So, S) : fmaf(Fo, S, So);
      F *= Fo;
      Fo = __shfl_xor(F, 32);
      So = __shfl_xor(S, 32);
      S = (quad & 2) ? fmaf(F, So, S) : fmaf(Fo, S, So);
      F *= Fo;
      Fseg[mi] = F; Sseg[mi] = S;
    }
    if (quad == 0) {
      #pragma unroll
      for (int j = 0; j < 2; ++j) {
        // sub covers t [base,base+32): mi=2j is the earlier half
        const float Fsub = Fseg[2 * j + 1] * Fseg[2 * j];
        const float Ssub = fmaf(Fseg[2 * j + 1], Sseg[2 * j], Sseg[2 * j + 1]);
        const int subl = (wave & 1) * 2 + j;
        const int sidx = cc * 4 + subl;
        const int seq = bb * 512 + hb * 64 + hl;
        Fc[(size_t)sidx * SEQS_ + seq] = Fsub;
        Sc[(size_t)sidx * SEQS_ + seq] = Ssub;
      }
    }
  }
}

// ---------------------------------------------------------------------------
// Kernel 3: carry scan, LDS-local. Block owns 32 seqs: stages all 256
// sub-chunk (F,S) into LDS, hierarchical scan, writes Hin + out[:,0,:].
// ---------------------------------------------------------------------------
__global__ __launch_bounds__(256, 2)
void scan_pass2(const float* __restrict__ h0, const float* __restrict__ Fc,
                const float* __restrict__ Sc, float* __restrict__ Hin,
                float* __restrict__ out) {
  __shared__ float Fs[NSUB_ * 32];    // 32 KB  [sub][sl]
  __shared__ float Ss[NSUB_ * 32];    // 32 KB
  __shared__ float Fg[8 * 32], Sg[8 * 32], Hg[8 * 32];

  const int tid = threadIdx.x;
  const int seq0 = blockIdx.x * 32;

  #pragma unroll 8
  for (int i = tid; i < NSUB_ * 32; i += 256) {
    const int sub = i >> 5;
    const int sl = i & 31;
    Fs[i] = Fc[(size_t)sub * SEQS_ + seq0 + sl];
    Ss[i] = Sc[(size_t)sub * SEQS_ + seq0 + sl];
  }
  __syncthreads();

  const int g = tid >> 5;             // group 0..7 (32 subs each)
  const int sl = tid & 31;
  {
    float F = 1.f, S = 0.f;
    #pragma unroll 8
    for (int j = 0; j < 32; ++j) {
      const int idx = (g * 32 + j) * 32 + sl;
      S = fmaf(Fs[idx], S, Ss[idx]);
      F *= Fs[idx];
    }
    Fg[g * 32 + sl] = F;
    Sg[g * 32 + sl] = S;
  }
  __syncthreads();

  if (tid < 32) {
    const int seq = seq0 + tid;
    const int b = seq >> 9;
    const int h = seq & 511;
    const float xv = h0[seq];
    float hcur = (xv >= 0.f) ? (xv + 0.5f) : (1.f / (1.f + __expf(-xv)));
    out[(size_t)(b * (T_ + 1)) * H_ + h] = hcur;
    #pragma unroll
    for (int gg = 0; gg < 8; ++gg) {
      Hg[gg * 32 + tid] = hcur;
      hcur = fmaf(Fg[gg * 32 + tid], hcur, Sg[gg * 32 + tid]);
    }
  }
  __syncthreads();

  float h = Hg[g * 32 + sl];
  #pragma unroll 8
  for (int j = 0; j < 32; ++j) {
    const int sub = g * 32 + j;
    const int idx = sub * 32 + sl;
    Hin[(size_t)sub * SEQS_ + seq0 + sl] = h;
    h = fmaf(Fs[idx], h, Ss[idx]);
  }
}

// ---------------------------------------------------------------------------
// Kernel 4: fix-up — replay 32-step sub-chunks with carried h_in. 2048 blocks.
// ---------------------------------------------------------------------------
__global__ void scan_pass3(const unsigned int* __restrict__ AV,
                           const float* __restrict__ Hin, float* __restrict__ out) {
  const int gid = blockIdx.x * 256 + threadIdx.x;
  const int hl = gid & 63;
  const int rest = gid >> 6;          // hbi(3) sub(2) c(6) b(2)
  const int hbi = rest & 7;
  const int sub = (rest >> 3) & 3;
  const int c = (rest >> 5) & 63;
  const int b = rest >> 11;
  const unsigned int* p = AV + (size_t)((b * 64 + c) * 8 + hbi) * (CHUNK_ * 64)
                             + sub * SUB_ * 64 + hl;
  float* o = out + ((size_t)(b * (T_ + 1) + c * CHUNK_ + sub * SUB_ + 1) * H_)
                 + hbi * 64 + hl;
  const int seq = b * 512 + hbi * 64 + hl;
  float hcur = Hin[(size_t)(c * 4 + sub) * SEQS_ + seq];
  #pragma unroll 8
  for (int t = 0; t < SUB_; ++t) {
    const unsigned int w = p[t * 64];
    const float a = bf2f((unsigned short)(w & 0xffffu));
    const float v = bf2f((unsigned short)(w >> 16));
    hcur = fmaf(a, hcur, v);
    o[(size_t)t * H_] = hcur;
  }
}

extern "C" void kernel_launch(void* const* d_in, const int* in_sizes, int n_in,
                              void* d_out, int out_size, void* d_ws, size_t ws_size,
                              hipStream_t stream) {
  const float* x  = (const float*)d_in[0];
  const float* h0 = (const float*)d_in[1];
  const float* Wf = (const float*)d_in[2];
  const float* bF = (const float*)d_in[3];
  const float* Wi = (const float*)d_in[4];
  const float* bI = (const float*)d_in[5];
  const float* Wh = (const float*)d_in[6];
  const float* bH = (const float*)d_in[7];
  float* out = (float*)d_out;

  char* ws = (char*)d_ws;
  size_t off = 0;
  unsigned int* AV = (unsigned int*)(ws + off);      off += (size_t)M_ * H_ * 4;      // 64 MB
  unsigned short* xbf = (unsigned short*)(ws + off); off += (size_t)M_ * D_ * 2;      // 32 MB
  unsigned short* Wt = (unsigned short*)(ws + off);  off += (size_t)3 * H_ * D_ * 2;  // 1.5 MB
  float* Fc  = (float*)(ws + off); off += (size_t)NSUB_ * SEQS_ * 4;                  // 2 MB
  float* Sc  = (float*)(ws + off); off += (size_t)NSUB_ * SEQS_ * 4;                  // 2 MB
  float* Hin = (float*)(ws + off); off += (size_t)NSUB_ * SEQS_ * 4;                  // 2 MB

  convert_all<<<(M_ * D_ / 4) / 256, 256, 0, stream>>>(x, Wf, Wi, Wh, xbf, Wt);
  gemm_gates<<<2048, 256, 0, stream>>>(xbf, Wt, bF, bI, bH, AV, Fc, Sc);
  scan_pass2<<<SEQS_ / 32, 256, 0, stream>>>(h0, Fc, Sc, Hin, out);
  scan_pass3<<<(SEQS_ * NSUB_) / 256, 256, 0, stream>>>(AV, Hin, out);
}